// Round 7
// baseline (266.699 us; speedup 1.0000x reference)
//
#include <hip/hip_runtime.h>

#define OUTHALF 8388608
#define CPAD    320
#define MARGIN  7.5e-4f
#define CAP     24

typedef float f32x4 __attribute__((ext_vector_type(4)));
typedef short bf16x8 __attribute__((ext_vector_type(8)));

__device__ __forceinline__ unsigned short f2bf(float x) {   // RNE fp32 -> bf16
    unsigned u = __float_as_uint(x);
    return (unsigned short)((u + 0x7FFFu + ((u >> 16) & 1u)) >> 16);
}
__device__ __forceinline__ unsigned fkey(float f) {         // order-preserving f32->u32
    unsigned b = __float_as_uint(f);
    return b ^ ((b & 0x80000000u) ? 0xFFFFFFFFu : 0x80000000u);
}
__device__ __forceinline__ float finv(unsigned k) {
    unsigned b = k ^ ((k & 0x80000000u) ? 0x80000000u : 0xFFFFFFFFu);
    return __uint_as_float(b);
}
__device__ __forceinline__ void atomicMinU64(unsigned long long* p, unsigned long long v) {
    unsigned long long cur = *p;
    while (v < cur) {
        unsigned long long old = atomicCAS(p, cur, v);
        if (old == cur) break;
        cur = old;
    }
}

// ---- kernel A1: zplane (bf16 [32768][320], slot256=1.0) + exact z2 ----
__global__ __launch_bounds__(256) void prep_z(const float* __restrict__ z,
                                              float* __restrict__ out) {
    __shared__ float tile[64][65];
    const int t = threadIdx.x;
    const int n0 = blockIdx.x * 64;
    const int b = n0 >> 10, hw0 = n0 & 1023;
    const float* zb = z + (size_t)b * 262144 + hw0;
    unsigned short* zpl = (unsigned short*)out;

    for (int ch = 0; ch < 4; ++ch) {
        __syncthreads();
        #pragma unroll
        for (int r = 0; r < 16; ++r) {
            int c = r * 4 + (t >> 6);
            int nn = t & 63;
            tile[c][nn] = zb[(size_t)(ch * 64 + c) * 1024 + nn];
        }
        __syncthreads();
        #pragma unroll
        for (int i = 0; i < 2; ++i) {
            int id = i * 256 + t;
            int row = id >> 3, seg = id & 7;
            unsigned short tmp[8];
            #pragma unroll
            for (int j = 0; j < 8; ++j) tmp[j] = f2bf(tile[seg * 8 + j][row]);
            *(uint4*)(zpl + (size_t)(n0 + row) * CPAD + ch * 64 + seg * 8) = *(const uint4*)tmp;
        }
    }
    if (t < 64) {
        const float* p = zb + t;
        float s = 0.0f;
        #pragma unroll 8
        for (int c = 0; c < 256; ++c) { float v = p[(size_t)c * 1024]; s = fmaf(v, v, s); }
        ((float*)(out + OUTHALF + 262144))[n0 + t] = s;   // exact z2
        unsigned short* rowp = zpl + (size_t)(n0 + t) * CPAD + 256;
        rowp[0] = 0x3F80;                                  // bf16(1.0)
        for (int j = 1; j < 64; ++j) rowp[j] = 0;
    }
}

// ---- kernel A2: wplane (bf16 [1024][320], slot256=bf16(-w2/2)) + exact w2 ----
__global__ __launch_bounds__(256) void prep_w(const float* __restrict__ w,
                                              float* __restrict__ out) {
    const int k = blockIdx.x * 256 + threadIdx.x;
    if (k >= 1024) return;
    unsigned short* wpl = (unsigned short*)(out + OUTHALF);
    const float4* row = (const float4*)(w + (size_t)k * 256);
    float s = 0.0f;
    #pragma unroll 4
    for (int c4 = 0; c4 < 64; ++c4) {
        float4 v = row[c4];
        s += v.x * v.x;
        s += v.y * v.y;
        s += v.z * v.z;
        s += v.w * v.w;
        unsigned short t4[4] = {f2bf(v.x), f2bf(v.y), f2bf(v.z), f2bf(v.w)};
        *(uint2*)(wpl + (size_t)k * CPAD + c4 * 4) = *(const uint2*)t4;
    }
    ((float*)(out + OUTHALF + 262144 + 32768))[k] = s;     // exact w2
    unsigned short* rowp = wpl + (size_t)k * CPAD + 256;
    rowp[0] = f2bf(-0.5f * s);
    for (int j = 1; j < 64; ++j) rowp[j] = 0;
}

// ---- kernel B: MFMA approx scores + candidate collection + exact recheck ----
__global__ __launch_bounds__(256) void vq_main(const float* __restrict__ z,
                                               const float* __restrict__ w,
                                               float* __restrict__ out) {
    __shared__ uint4 ztb[128 * 9];          // 128 n-rows x 144 B (64c bf16 + pad)
    __shared__ unsigned rmink[128];
    __shared__ unsigned cnt[128];
    __shared__ unsigned candk[128 * CAP];
    __shared__ unsigned long long best[128];
    __shared__ unsigned short ovlist[128];
    __shared__ unsigned ovcnt;

    const int t = threadIdx.x;
    const int lane = t & 63;
    const int wid = t >> 6;
    const int n0 = blockIdx.x * 128;
    const int l15 = lane & 15;
    const int lq  = lane >> 4;

    const unsigned short* zpl = (const unsigned short*)out;
    const unsigned short* wpl = (const unsigned short*)(out + OUTHALF);
    const float* z2arr = (const float*)(out + OUTHALF + 262144);
    const float* w2arr = (const float*)(out + OUTHALF + 262144 + 32768);

    for (int i = t; i < 128; i += 256) {
        rmink[i] = 0xFF7FFFFFu;             // fkey(FLT_MAX)
        cnt[i] = 0;
        best[i] = ~0ull;
    }
    if (t == 0) ovcnt = 0;

    #pragma unroll 1
    for (int pass = 0; pass < 8; ++pass) {
        const int kbase = pass * 128 + wid * 32;
        f32x4 acc[2][8];
        #pragma unroll
        for (int kt = 0; kt < 2; ++kt)
            #pragma unroll
            for (int sub = 0; sub < 8; ++sub) acc[kt][sub] = 0.0f;

        #pragma unroll 1
        for (int chunk = 0; chunk < 5; ++chunk) {
            __syncthreads();
            #pragma unroll
            for (int i = 0; i < 4; ++i) {
                int id = i * 256 + t;
                int row = id >> 3, seg = id & 7;
                ztb[row * 9 + seg] =
                    *(const uint4*)(zpl + (size_t)(n0 + row) * CPAD + chunk * 64 + seg * 8);
            }
            __syncthreads();
            #pragma unroll
            for (int step = 0; step < 2; ++step) {
                const int cs = chunk * 64 + step * 32;
                bf16x8 afr[2];
                #pragma unroll
                for (int kt = 0; kt < 2; ++kt) {
                    int rowk = kbase + kt * 16 + l15;
                    afr[kt] = *(const bf16x8*)(wpl + (size_t)rowk * CPAD + cs + lq * 8);
                }
                #pragma unroll
                for (int sub = 0; sub < 8; ++sub) {
                    int n = sub * 16 + l15;
                    bf16x8 bfr = *(const bf16x8*)((const unsigned short*)ztb + n * 72 + step * 32 + lq * 8);
                    #pragma unroll
                    for (int kt = 0; kt < 2; ++kt)
                        acc[kt][sub] = __builtin_amdgcn_mfma_f32_16x16x32_bf16(
                            afr[kt], bfr, acc[kt][sub], 0, 0, 0);
                }
            }
        }
        // finalize pass (a): settle per-n running min
        #pragma unroll
        for (int sub = 0; sub < 8; ++sub) {
            int n = sub * 16 + l15;
            float m = 3.4e38f;
            #pragma unroll
            for (int kt = 0; kt < 2; ++kt)
                #pragma unroll
                for (int r = 0; r < 4; ++r) m = fminf(m, -2.0f * acc[kt][sub][r]);
            atomicMin(&rmink[n], fkey(m));
        }
        __syncthreads();
        // finalize pass (c): append all k within margin of settled min
        #pragma unroll
        for (int sub = 0; sub < 8; ++sub) {
            int n = sub * 16 + l15;
            float thr = finv(rmink[n]) + MARGIN;
            #pragma unroll
            for (int kt = 0; kt < 2; ++kt)
                #pragma unroll
                for (int r = 0; r < 4; ++r) {
                    float s = -2.0f * acc[kt][sub][r];
                    if (s <= thr) {
                        unsigned slot = atomicAdd(&cnt[n], 1u);
                        if (slot < CAP) candk[n * CAP + slot] = (unsigned)(kbase + kt * 16 + lq * 4 + r);
                    }
                }
        }
        __syncthreads();
    }

    // overflow list
    if (t < 128 && cnt[t] > CAP) {
        unsigned o = atomicAdd(&ovcnt, 1u);
        ovlist[o] = (unsigned short)t;
    }
    // exact recheck of candidates (reference chain: sequential-c fmaf, first-index ties)
    #pragma unroll 1
    for (int p = t; p < 128 * CAP; p += 256) {
        int nl = p / CAP, slot = p % CAP;
        unsigned c_ = cnt[nl];
        if (c_ > CAP || slot >= (int)c_) continue;
        unsigned k = candk[p];
        int n = n0 + nl;
        const float* zc = z + (size_t)(n >> 10) * 262144 + (n & 1023);
        const float* wr = w + (size_t)k * 256;
        float s = 0.0f;
        #pragma unroll 8
        for (int c = 0; c < 256; ++c) s = fmaf(zc[(size_t)c * 1024], wr[c], s);
        float d = fmaf(-2.0f, s, z2arr[n]) + w2arr[k];
        atomicMinU64(&best[nl], ((unsigned long long)__float_as_uint(d) << 32) | k);
    }
    __syncthreads();
    // rare fallback: full exact scan for overflowed n (one wave per n)
    for (unsigned o = wid; o < ovcnt; o += 4) {
        int nl = ovlist[o];
        int n = n0 + nl;
        const float* zc = z + (size_t)(n >> 10) * 262144 + (n & 1023);
        unsigned long long m = ~0ull;
        for (int kk = lane; kk < 1024; kk += 64) {
            const float* wr = w + (size_t)kk * 256;
            float s = 0.0f;
            #pragma unroll 8
            for (int c = 0; c < 256; ++c) s = fmaf(zc[(size_t)c * 1024], wr[c], s);
            float d = fmaf(-2.0f, s, z2arr[n]) + w2arr[kk];
            unsigned long long key = ((unsigned long long)__float_as_uint(d) << 32) | (unsigned)kk;
            m = (key < m) ? key : m;
        }
        #pragma unroll
        for (int sh = 1; sh <= 32; sh <<= 1) {
            unsigned long long o2 = __shfl_xor(m, sh, 64);
            m = (o2 < m) ? o2 : m;
        }
        if (lane == 0) atomicMinU64(&best[nl], m);
    }
    __syncthreads();
    if (t < 128) out[(size_t)2 * OUTHALF + n0 + t] = (float)(unsigned)(best[t] & 0xFFFFFFFFu);
}

// ---- kernel C: gather + write code/detached (round-5 proven epilogue) ----
__global__ __launch_bounds__(256) void epilogue(const float* __restrict__ z,
                                                const float* __restrict__ w,
                                                float* __restrict__ out) {
    const int t = threadIdx.x;
    const int n0 = blockIdx.x * 32;
    const int b = n0 >> 10, hw0 = n0 & 1023;
    const int n = t & 31;
    const int q = t >> 5;
    const int kn = (int)out[(size_t)2 * OUTHALF + n0 + n];
    const float* wrow = w + (size_t)kn * 256;
    const size_t obase = (size_t)b * 262144 + hw0;
    #pragma unroll
    for (int cc = 0; cc < 8; ++cc) {
        const int c0 = (q + cc * 8) * 4;
        const float4 cv = *(const float4*)(wrow + c0);
        const float cvf[4] = {cv.x, cv.y, cv.z, cv.w};
        #pragma unroll
        for (int u = 0; u < 4; ++u) {
            const size_t off = obase + (size_t)(c0 + u) * 1024 + n;
            const float zz = z[off];
            out[off] = cvf[u];
            out[OUTHALF + off] = (cvf[u] - zz) + zz;   // reference rounding chain
        }
    }
}

extern "C" void kernel_launch(void* const* d_in, const int* in_sizes, int n_in,
                              void* d_out, int out_size, void* d_ws, size_t ws_size,
                              hipStream_t stream) {
    const float* z = (const float*)d_in[0];
    const float* w = (const float*)d_in[1];
    float* out = (float*)d_out;
    prep_z  <<<512, 256, 0, stream>>>(z, out);
    prep_w  <<<4,   256, 0, stream>>>(w, out);
    vq_main <<<256, 256, 0, stream>>>(z, w, out);
    epilogue<<<1024, 256, 0, stream>>>(z, w, out);
}